// Round 14
// baseline (646.133 us; speedup 1.0000x reference)
//
#include <hip/hip_runtime.h>
#include <hip/hip_bf16.h>
#include <stdint.h>

#define N_NODES 100000
#define N_EDGES 1600000
#define N_GRAPHS 512
#define IN_F 50
#define HID 128

#define NPART 256
#define PART_NODES ((N_NODES + NPART - 1) / NPART)   // 391 (256*391 = 100096)
#define BCAP 7600                                     // per-bucket cap (mean 6250 + slack)
#define LBITS 9                                       // local_dst bits (391 < 512)

typedef __attribute__((ext_vector_type(8))) short bf16x8;
typedef __attribute__((ext_vector_type(4))) float f32x4;

__device__ __forceinline__ float bf2f(unsigned short s) {
    return __uint_as_float(((unsigned)s) << 16);
}
__device__ __forceinline__ unsigned short f2bf(float f) {
    unsigned u = __float_as_uint(f);
    u = (u + 0x7FFFu + ((u >> 16) & 1u)) >> 16;   // round-to-nearest-even
    return (unsigned short)u;
}

// ---------------- fused prep: xconv | zero bucket_cnt + rowptr tail | wconv | graph_ranges ----------------
#define PREP_W2 (N_NODES * 64)
#define PREP_W0 (NPART + 1)
#define PREP_W1 (128 * 64 + 128 * 128)
#define PREP_W3 (N_GRAPHS + 1)
#define PREP_TOTAL (PREP_W2 + PREP_W0 + PREP_W1 + PREP_W3)

__global__ __launch_bounds__(256) void prep_all(
    const float* __restrict__ x, unsigned short* __restrict__ xbf,
    int* __restrict__ bucket_cnt, int* __restrict__ rowptr,
    const float* __restrict__ Wr1, const float* __restrict__ Wo1,
    const float* __restrict__ Wr2, const float* __restrict__ Wo2,
    const float* __restrict__ Wr3, const float* __restrict__ Wo3,
    unsigned short* __restrict__ o_r1, unsigned short* __restrict__ o_o1,
    unsigned short* __restrict__ o_r2, unsigned short* __restrict__ o_o2,
    unsigned short* __restrict__ o_r3, unsigned short* __restrict__ o_o3,
    const int* __restrict__ batch, int* __restrict__ gstart) {
    int idx = blockIdx.x * 256 + threadIdx.x;
    if (idx < PREP_W2) {                         // xconv: x[100k][50] f32 -> xbf[100k][64] bf16
        int n = idx >> 6, c = idx & 63;
        float v = (c < IN_F) ? x[(size_t)n * IN_F + c] : 0.f;
        xbf[idx] = f2bf(v);
        return;
    }
    idx -= PREP_W2;
    if (idx < PREP_W0) {
        if (idx < NPART) bucket_cnt[idx] = 0;
        else rowptr[N_NODES] = N_EDGES;
        return;
    }
    idx -= PREP_W0;
    if (idx < PREP_W1) {                         // weight f32 -> bf16 (layer1 padded 50->64)
        if (idx < 128 * 64) {
            int n = idx >> 6, k = idx & 63;
            unsigned short a = 0, b = 0;
            if (k < IN_F) { a = f2bf(Wr1[n * IN_F + k]); b = f2bf(Wo1[n * IN_F + k]); }
            o_r1[idx] = a; o_o1[idx] = b;
        } else {
            int i2 = idx - 128 * 64;
            o_r2[i2] = f2bf(Wr2[i2]); o_o2[i2] = f2bf(Wo2[i2]);
            o_r3[i2] = f2bf(Wr3[i2]); o_o3[i2] = f2bf(Wo3[i2]);
        }
        return;
    }
    idx -= PREP_W1;
    if (idx < PREP_W3) {                         // graph_ranges (batch sorted)
        if (idx == N_GRAPHS) { gstart[idx] = N_NODES; return; }
        int lo = 0, hi = N_NODES;
        while (lo < hi) { int m = (lo + hi) >> 1; if (batch[m] < idx) lo = m + 1; else hi = m; }
        gstart[idx] = lo;
    }
}

// ---------------- CSR build: bucket by dst partition, then LDS-cursor local CSR ----------------
#define B1_BLOCKS 512
#define B1_EPT ((N_EDGES + B1_BLOCKS * 256 - 1) / (B1_BLOCKS * 256))   // 13

__global__ __launch_bounds__(256) void bucket_scatter(const int* __restrict__ src,
                                                      const int* __restrict__ dst,
                                                      int* __restrict__ bucket_cnt,
                                                      unsigned* __restrict__ pairs) {
    __shared__ int cnt[NPART], base[NPART];
    int t = threadIdx.x;
    for (int i = t; i < NPART; i += 256) cnt[i] = 0;
    __syncthreads();
    const int blockStart = blockIdx.x * (256 * B1_EPT);
    int kk[B1_EPT];
    unsigned ww[B1_EPT];
#pragma unroll
    for (int i = 0; i < B1_EPT; i++) {
        int e = blockStart + i * 256 + t;
        if (e < N_EDGES) {
            int d = dst[e];
            int k = d / PART_NODES;
            int local = d - k * PART_NODES;
            kk[i] = k;
            ww[i] = ((unsigned)src[e] << LBITS) | (unsigned)local;
            atomicAdd(&cnt[k], 1);
        } else kk[i] = -1;
    }
    __syncthreads();
    for (int i = t; i < NPART; i += 256) { base[i] = atomicAdd(&bucket_cnt[i], cnt[i]); cnt[i] = 0; }
    __syncthreads();
#pragma unroll
    for (int i = 0; i < B1_EPT; i++) {
        int k = kk[i];
        if (k >= 0) {
            int p = base[k] + atomicAdd(&cnt[k], 1);
            pairs[(size_t)k * BCAP + p] = ww[i];
        }
    }
}

// one block per partition: LDS histogram -> block scan -> rowptr -> LDS-cursor fill.
// Zero global atomics (device-scope atomics are fabric round-trips regardless of locality).
#define LCSR_T 256
#define LCH ((PART_NODES + LCSR_T - 1) / LCSR_T)    // 2

__global__ __launch_bounds__(LCSR_T) void local_csr(const int* __restrict__ bucket_cnt,
                                                    const unsigned* __restrict__ pairs,
                                                    int* __restrict__ rowptr,
                                                    int* __restrict__ csr_src) {
    __shared__ int cur[PART_NODES];
    __shared__ int red[LCSR_T];
    __shared__ int pb[NPART];
    const int p = blockIdx.x, t = threadIdx.x;
    const int cnt = bucket_cnt[p];
    const unsigned* bp = pairs + (size_t)p * BCAP;
    const int plo = p * PART_NODES;

    for (int i = t; i < PART_NODES; i += LCSR_T) cur[i] = 0;
    if (t < NPART) pb[t] = bucket_cnt[t];
    __syncthreads();
    if (t == 0) {
        int s = 0;
        for (int i = 0; i < NPART; i++) { int v = pb[i]; pb[i] = s; s += v; }
    }
    for (int i = t; i < cnt; i += LCSR_T) atomicAdd(&cur[bp[i] & ((1u << LBITS) - 1u)], 1);
    __syncthreads();
    const int pbase = pb[p];
    int e[LCH];
    int s = 0;
#pragma unroll
    for (int i = 0; i < LCH; i++) {
        int idx = t * LCH + i;
        e[i] = (idx < PART_NODES) ? cur[idx] : 0;
        s += e[i];
    }
    red[t] = s;
    __syncthreads();
    for (int o = 1; o < LCSR_T; o <<= 1) {
        int u = (t >= o) ? red[t - o] : 0;
        __syncthreads();
        red[t] += u;
        __syncthreads();
    }
    int run = red[t] - s;
#pragma unroll
    for (int i = 0; i < LCH; i++) {
        int idx = t * LCH + i;
        if (idx < PART_NODES) {
            cur[idx] = run;
            int node = plo + idx;
            if (node < N_NODES) rowptr[node] = pbase + run;
            run += e[i];
        }
    }
    __syncthreads();
    for (int i = t; i < cnt; i += LCSR_T) {
        unsigned v = bp[i];
        int pos = pbase + atomicAdd(&cur[v & ((1u << LBITS) - 1u)], 1);
        csr_src[pos] = (int)(v >> LBITS);
    }
}

// ---------------- fused gather + MFMA layer ----------------
// out = [relu]( Agg(hsrc) @ B1^T + bias + hsrc @ B2^T ), hsrc bf16 [N][K], out bf16 [N][128].
// Phase 1: block gathers its 128 rows' aggregation into LDS A-tile (pitch-padded).
// Phase 2: 4 waves x 32 rows MFMA; A-agg from LDS, A-root from global (own rows,
// coalesced), WEIGHTS from global (32KB, L2-hot in every XCD; ~200MB L2 reads/dispatch
// = ~6us; keeps LDS at one A-tile -> 4 blocks/CU = 16 waves for gather latency hiding).
// NOT in-place: hsrc buffers are read-only during the launch (ping-pong h1/h2) --
// fusing removed the gather/mfma barrier that made in-place safe.
template <int K, bool RELU>
__global__ __launch_bounds__(256) void fused_layer(
    const unsigned short* __restrict__ hsrc,
    const int* __restrict__ rowptr, const int* __restrict__ csr_src,
    const unsigned short* __restrict__ B1, const unsigned short* __restrict__ B2,
    const float* __restrict__ bias, unsigned short* __restrict__ hout) {
    constexpr int PITCH = K * 2 + 16;            // bytes; breaks stride-2^n bank conflicts
    __shared__ __align__(16) unsigned char atile[128 * PITCH];
    const int tid = threadIdx.x;
    const int m0 = blockIdx.x * 128;

    // ---- phase 1: gather aggregation of this block's 128 rows into LDS ----
    {
        constexpr int CL = K / 4;                // uint2 lanes per row (32 or 16)
        constexpr int NG = 256 / CL;             // node groups per block (8 or 16)
        constexpr int NPG = 128 / NG;            // nodes per group (16 or 8)
        const int grp = tid / CL, c = tid % CL;
        const uint2* hu = reinterpret_cast<const uint2*>(hsrc);
        for (int ni = 0; ni < NPG; ni++) {
            int nl = grp * NPG + ni;
            int n = m0 + nl; if (n > N_NODES - 1) n = N_NODES - 1;
            int jb = rowptr[n], je = rowptr[n + 1];
            float a0 = 0.f, a1 = 0.f, a2 = 0.f, a3 = 0.f;
            int j = jb;
            for (; j + 3 < je; j += 4) {
                int s0 = csr_src[j], s1 = csr_src[j + 1], s2 = csr_src[j + 2], s3 = csr_src[j + 3];
                uint2 v0 = hu[(size_t)s0 * CL + c];
                uint2 v1 = hu[(size_t)s1 * CL + c];
                uint2 v2 = hu[(size_t)s2 * CL + c];
                uint2 v3 = hu[(size_t)s3 * CL + c];
                a0 += (bf2f(v0.x & 0xFFFF) + bf2f(v1.x & 0xFFFF)) + (bf2f(v2.x & 0xFFFF) + bf2f(v3.x & 0xFFFF));
                a1 += (bf2f(v0.x >> 16) + bf2f(v1.x >> 16)) + (bf2f(v2.x >> 16) + bf2f(v3.x >> 16));
                a2 += (bf2f(v0.y & 0xFFFF) + bf2f(v1.y & 0xFFFF)) + (bf2f(v2.y & 0xFFFF) + bf2f(v3.y & 0xFFFF));
                a3 += (bf2f(v0.y >> 16) + bf2f(v1.y >> 16)) + (bf2f(v2.y >> 16) + bf2f(v3.y >> 16));
            }
            for (; j < je; j++) {
                int s0 = csr_src[j];
                uint2 v0 = hu[(size_t)s0 * CL + c];
                a0 += bf2f(v0.x & 0xFFFF);
                a1 += bf2f(v0.x >> 16);
                a2 += bf2f(v0.y & 0xFFFF);
                a3 += bf2f(v0.y >> 16);
            }
            uint2 pk;
            pk.x = (unsigned)f2bf(a0) | ((unsigned)f2bf(a1) << 16);
            pk.y = (unsigned)f2bf(a2) | ((unsigned)f2bf(a3) << 16);
            *reinterpret_cast<uint2*>(&atile[nl * PITCH + c * 8]) = pk;
        }
    }
    __syncthreads();

    // ---- phase 2: MFMA. D = W_frag x A_frag -> lane&15 = node, (lane>>4)*4+reg = out col ----
    const int lane = tid & 63;
    const int wave = tid >> 6;
    const int ar = lane & 15;
    const int kh = lane >> 4;

    f32x4 acc0[8], acc1[8];
#pragma unroll
    for (int nt = 0; nt < 8; nt++) {
        acc0[nt] = (f32x4){0.f, 0.f, 0.f, 0.f};
        acc1[nt] = (f32x4){0.f, 0.f, 0.f, 0.f};
    }

    // aggregated term: A from LDS, B1 from global (L2-hot)
#pragma unroll
    for (int ks = 0; ks < K / 32; ks++) {
        bf16x8 a0 = *reinterpret_cast<const bf16x8*>(
            &atile[(wave * 32 + ar) * PITCH + ks * 64 + kh * 16]);
        bf16x8 a1 = *reinterpret_cast<const bf16x8*>(
            &atile[(wave * 32 + 16 + ar) * PITCH + ks * 64 + kh * 16]);
#pragma unroll
        for (int nt = 0; nt < 8; nt++) {
            bf16x8 b = *reinterpret_cast<const bf16x8*>(B1 + (size_t)(nt * 16 + ar) * K + ks * 32 + kh * 8);
            acc0[nt] = __builtin_amdgcn_mfma_f32_16x16x32_bf16(b, a0, acc0[nt], 0, 0, 0);
            acc1[nt] = __builtin_amdgcn_mfma_f32_16x16x32_bf16(b, a1, acc1[nt], 0, 0, 0);
        }
    }
    // root term: A from global (own rows, coalesced), B2 from global (L2-hot)
    {
        int r0 = m0 + wave * 32 + ar;      if (r0 > N_NODES - 1) r0 = N_NODES - 1;
        int r1 = m0 + wave * 32 + 16 + ar; if (r1 > N_NODES - 1) r1 = N_NODES - 1;
        const unsigned short* a0p = hsrc + (size_t)r0 * K + kh * 8;
        const unsigned short* a1p = hsrc + (size_t)r1 * K + kh * 8;
#pragma unroll
        for (int ks = 0; ks < K / 32; ks++) {
            bf16x8 a0 = *reinterpret_cast<const bf16x8*>(a0p + ks * 32);
            bf16x8 a1 = *reinterpret_cast<const bf16x8*>(a1p + ks * 32);
#pragma unroll
            for (int nt = 0; nt < 8; nt++) {
                bf16x8 b = *reinterpret_cast<const bf16x8*>(B2 + (size_t)(nt * 16 + ar) * K + ks * 32 + kh * 8);
                acc0[nt] = __builtin_amdgcn_mfma_f32_16x16x32_bf16(b, a0, acc0[nt], 0, 0, 0);
                acc1[nt] = __builtin_amdgcn_mfma_f32_16x16x32_bf16(b, a1, acc1[nt], 0, 0, 0);
            }
        }
    }

    // ---- epilogue: lane holds 4 consecutive out-cols per nt per m-tile ----
    float4 bv[8];
#pragma unroll
    for (int nt = 0; nt < 8; nt++)
        bv[nt] = *reinterpret_cast<const float4*>(bias + nt * 16 + kh * 4);

    int node0 = m0 + wave * 32 + ar;
    int node1 = m0 + wave * 32 + 16 + ar;
    if (node0 < N_NODES) {
#pragma unroll
        for (int nt = 0; nt < 8; nt++) {
            float v0 = acc0[nt][0] + bv[nt].x;
            float v1 = acc0[nt][1] + bv[nt].y;
            float v2 = acc0[nt][2] + bv[nt].z;
            float v3 = acc0[nt][3] + bv[nt].w;
            if (RELU) { v0 = fmaxf(v0, 0.f); v1 = fmaxf(v1, 0.f); v2 = fmaxf(v2, 0.f); v3 = fmaxf(v3, 0.f); }
            uint2 pk;
            pk.x = (unsigned)f2bf(v0) | ((unsigned)f2bf(v1) << 16);
            pk.y = (unsigned)f2bf(v2) | ((unsigned)f2bf(v3) << 16);
            *reinterpret_cast<uint2*>(hout + (size_t)node0 * HID + nt * 16 + kh * 4) = pk;
        }
    }
    if (node1 < N_NODES) {
#pragma unroll
        for (int nt = 0; nt < 8; nt++) {
            float v0 = acc1[nt][0] + bv[nt].x;
            float v1 = acc1[nt][1] + bv[nt].y;
            float v2 = acc1[nt][2] + bv[nt].z;
            float v3 = acc1[nt][3] + bv[nt].w;
            if (RELU) { v0 = fmaxf(v0, 0.f); v1 = fmaxf(v1, 0.f); v2 = fmaxf(v2, 0.f); v3 = fmaxf(v3, 0.f); }
            uint2 pk;
            pk.x = (unsigned)f2bf(v0) | ((unsigned)f2bf(v1) << 16);
            pk.y = (unsigned)f2bf(v2) | ((unsigned)f2bf(v3) << 16);
            *reinterpret_cast<uint2*>(hout + (size_t)node1 * HID + nt * 16 + kh * 4) = pk;
        }
    }
}

// ---------------- fused mean-pool + final linear (atomic-free) ----------------
__global__ __launch_bounds__(256) void pool_final(const unsigned short* __restrict__ h3,
                                                  const int* __restrict__ gstart,
                                                  const float* __restrict__ W_lin,
                                                  const float* __restrict__ b_lin,
                                                  float* __restrict__ out) {
    __shared__ float pp[4][HID];
    int g = blockIdx.x, t = threadIdx.x;
    int wave = t >> 6, lane = t & 63;
    int s0 = gstart[g], s1 = gstart[g + 1];
    const unsigned* h3u = reinterpret_cast<const unsigned*>(h3);
    float a0 = 0.f, a1 = 0.f;
    for (int n = s0 + wave; n < s1; n += 4) {
        unsigned v = h3u[(size_t)n * 64 + lane];
        a0 += bf2f((unsigned short)(v & 0xFFFF));
        a1 += bf2f((unsigned short)(v >> 16));
    }
    pp[wave][2 * lane] = a0;
    pp[wave][2 * lane + 1] = a1;
    __syncthreads();
    if (wave == 0) {
        float c = fmaxf((float)(s1 - s0), 1.f);
        float r0 = ((pp[0][2 * lane] + pp[1][2 * lane]) + (pp[2][2 * lane] + pp[3][2 * lane])) / c;
        float r1 = ((pp[0][2 * lane + 1] + pp[1][2 * lane + 1]) + (pp[2][2 * lane + 1] + pp[3][2 * lane + 1])) / c;
        pp[0][2 * lane] = r0;
        pp[0][2 * lane + 1] = r1;
    }
    __syncthreads();
    if (t < 4) {
        float s = b_lin[t];
#pragma unroll 8
        for (int k = 0; k < HID; k++) s += pp[0][k] * W_lin[t * HID + k];
        out[g * 4 + t] = s;
    }
}

extern "C" void kernel_launch(void* const* d_in, const int* in_sizes, int n_in,
                              void* d_out, int out_size, void* d_ws, size_t ws_size,
                              hipStream_t stream) {
    (void)in_sizes; (void)n_in; (void)out_size; (void)ws_size;
    const float* x      = (const float*)d_in[0];
    const int*   ei     = (const int*)d_in[1];
    const int*   batch  = (const int*)d_in[2];
    const float* W_rel1 = (const float*)d_in[3];
    const float* b_rel1 = (const float*)d_in[4];
    const float* W_root1= (const float*)d_in[5];
    const float* W_rel2 = (const float*)d_in[6];
    const float* b_rel2 = (const float*)d_in[7];
    const float* W_root2= (const float*)d_in[8];
    const float* W_rel3 = (const float*)d_in[9];
    const float* b_rel3 = (const float*)d_in[10];
    const float* W_root3= (const float*)d_in[11];
    const float* W_lin  = (const float*)d_in[12];
    const float* b_lin  = (const float*)d_in[13];
    const int* src = ei;
    const int* dst = ei + N_EDGES;

    char* ws = (char*)d_ws;
    size_t off = 0;
    auto alloc = [&](size_t bytes) { void* p = ws + off; off += (bytes + 255) & ~(size_t)255; return p; };
    unsigned short* h1       = (unsigned short*)alloc((size_t)N_NODES * HID * 2); // L1 out; L3 out (h3)
    unsigned short* h2       = (unsigned short*)alloc((size_t)N_NODES * HID * 2); // L2 out
    unsigned short* xbf      = (unsigned short*)alloc((size_t)N_NODES * 64 * 2);
    int*            rowptr   = (int*)alloc((size_t)(N_NODES + 1) * 4);
    int*            csr_src  = (int*)alloc((size_t)N_EDGES * 4);
    unsigned*       pairs    = (unsigned*)alloc((size_t)NPART * BCAP * 4);        // 7.8 MB
    int*            bucket_cnt = (int*)alloc(NPART * 4);
    int*            gstart   = (int*)alloc((size_t)(N_GRAPHS + 1) * 4);
    unsigned short* Wb_rel1  = (unsigned short*)alloc(128 * 64 * 2);
    unsigned short* Wb_root1 = (unsigned short*)alloc(128 * 64 * 2);
    unsigned short* Wb_rel2  = (unsigned short*)alloc(128 * 128 * 2);
    unsigned short* Wb_root2 = (unsigned short*)alloc(128 * 128 * 2);
    unsigned short* Wb_rel3  = (unsigned short*)alloc(128 * 128 * 2);
    unsigned short* Wb_root3 = (unsigned short*)alloc(128 * 128 * 2);

    // ---- fused prep
    prep_all<<<(PREP_TOTAL + 255) / 256, 256, 0, stream>>>(
        x, xbf, bucket_cnt, rowptr, W_rel1, W_root1, W_rel2, W_root2, W_rel3, W_root3,
        Wb_rel1, Wb_root1, Wb_rel2, Wb_root2, Wb_rel3, Wb_root3, batch, gstart);

    // ---- CSR build
    bucket_scatter<<<B1_BLOCKS, 256, 0, stream>>>(src, dst, bucket_cnt, pairs);
    local_csr<<<NPART, LCSR_T, 0, stream>>>(bucket_cnt, pairs, rowptr, csr_src);

    const int LBLK = (N_NODES + 127) / 128;

    // ---- three fused layers (ping-pong buffers: xbf -> h1 -> h2 -> h1)
    fused_layer<64, true><<<LBLK, 256, 0, stream>>>(
        xbf, rowptr, csr_src, Wb_rel1, Wb_root1, b_rel1, h1);
    fused_layer<128, true><<<LBLK, 256, 0, stream>>>(
        h1, rowptr, csr_src, Wb_rel2, Wb_root2, b_rel2, h2);
    fused_layer<128, false><<<LBLK, 256, 0, stream>>>(
        h2, rowptr, csr_src, Wb_rel3, Wb_root3, b_rel3, h1);

    // ---- atomic-free mean-pool + final linear
    pool_final<<<N_GRAPHS, 256, 0, stream>>>(h1, gstart, W_lin, b_lin, (float*)d_out);
}